// Round 12
// baseline (301.282 us; speedup 1.0000x reference)
//
#include <hip/hip_runtime.h>
#include <math.h>

#define N_NODES 50000
#define N_EDGES 800000
#define DIM 256
#define SCAN_BLOCKS ((N_NODES + 255) / 256)   // 196
#define NXBLK 12500                           // (N_NODES*DIM/4)/256 blocks for x convert
#define NDEGBLK ((N_EDGES + 255) / 256)       // 3125

typedef short bf16x8 __attribute__((ext_vector_type(8)));
typedef float f32x4 __attribute__((ext_vector_type(4)));

__device__ __forceinline__ float bf2f(unsigned short u) {
    return __uint_as_float(((unsigned)u) << 16);
}
__device__ __forceinline__ unsigned short f2bf(float f) {
    unsigned u = __float_as_uint(f);
    return (unsigned short)((u + 0x7fffu + ((u >> 16) & 1u)) >> 16);  // RTNE
}

// ---- fused prologue: x->bf16 + W1/W2 transpose (flat) + deg_count ----
__global__ __launch_bounds__(256) void k_prep(const float* __restrict__ x,
                                              unsigned short* __restrict__ xb,
                                              const float* __restrict__ W1,
                                              unsigned short* __restrict__ W1t,
                                              const float* __restrict__ W2,
                                              unsigned short* __restrict__ W2t,
                                              const int* __restrict__ dst,
                                              int* __restrict__ ideg) {
    int bid = blockIdx.x;
    int tid = threadIdx.x;
    if (bid < NXBLK) {
        int i = bid * 256 + tid;              // one float4 per thread
        float4 v = ((const float4*)x)[i];
        ((ushort4*)xb)[i] = make_ushort4(f2bf(v.x), f2bf(v.y), f2bf(v.z), f2bf(v.w));
    } else if (bid < NXBLK + 256) {
        int n = bid - NXBLK;
        W1t[n * 256 + tid] = f2bf(W1[tid * 256 + n]);
    } else if (bid < NXBLK + 512) {
        int n = bid - NXBLK - 256;
        W2t[n * 256 + tid] = f2bf(W2[tid * 256 + n]);
    } else {
        int e = (bid - NXBLK - 512) * 256 + tid;
        if (e < N_EDGES) atomicAdd(&ideg[dst[e]], 1);
    }
}

// ---------------- CSR build ----------------

__global__ __launch_bounds__(256) void k_scan_block(const int* __restrict__ ideg,
                                                    int* __restrict__ rowptr,
                                                    int* __restrict__ blocksum) {
    __shared__ int s[256];
    int t = threadIdx.x;
    int i = blockIdx.x * 256 + t;
    int v = (i < N_NODES) ? ideg[i] : 0;
    s[t] = v;
    for (int off = 1; off < 256; off <<= 1) {
        __syncthreads();
        int add = (t >= off) ? s[t - off] : 0;
        __syncthreads();
        s[t] += add;
    }
    __syncthreads();
    if (i < N_NODES) rowptr[i] = s[t] - v;
    if (t == 255) blocksum[blockIdx.x] = s[255];
}

__global__ __launch_bounds__(256) void k_scan_add(int* __restrict__ rowptr,
                                                  const int* __restrict__ blocksum,
                                                  int* __restrict__ cursor,
                                                  const int* __restrict__ ideg,
                                                  float* __restrict__ dis) {
    __shared__ int s[256];
    int t = threadIdx.x;
    int v = (t < SCAN_BLOCKS) ? blocksum[t] : 0;
    s[t] = v;
    for (int off = 1; off < 256; off <<= 1) {
        __syncthreads();
        int add = (t >= off) ? s[t - off] : 0;
        __syncthreads();
        s[t] += add;
    }
    __syncthreads();
    int excl = s[t] - v;
    __syncthreads();
    s[t] = excl;
    __syncthreads();
    int off = s[blockIdx.x];

    int i = blockIdx.x * 256 + t;
    if (i < N_NODES) {
        int r = rowptr[i] + off;
        rowptr[i] = r;
        cursor[i] = r;
        dis[i] = rsqrtf((float)(ideg[i] + 1));
    }
    if (i == 0) rowptr[N_NODES] = N_EDGES;
}

// fill CSR: ONE 8-byte scatter per edge: {src, dis[src]} packed
__global__ void k_csr_fill(const int* __restrict__ src, const int* __restrict__ dst,
                           int* __restrict__ cursor,
                           unsigned long long* __restrict__ csr_pk,
                           const float* __restrict__ dis) {
    int e = blockIdx.x * blockDim.x + threadIdx.x;
    if (e < N_EDGES) {
        int s = src[e];
        int pos = atomicAdd(&cursor[dst[e]], 1);
        unsigned long long pk = (unsigned)s |
            ((unsigned long long)__float_as_uint(dis[s]) << 32);
        __builtin_nontemporal_store(pk, &csr_pk[pos]);
    }
}

// ---------------- aggregation (bf16 gather, f32 accum, packed csr stream) ----------------
__global__ __launch_bounds__(256) void k_agg_bf16(const unsigned short* __restrict__ in,
                                                  const float* __restrict__ dis,
                                                  const int* __restrict__ rowptr,
                                                  const unsigned long long* __restrict__ csr_pk,
                                                  unsigned short* __restrict__ out) {
    int node = blockIdx.x * 4 + (threadIdx.x >> 6);
    if (node >= N_NODES) return;
    int lane = threadIdx.x & 63;
    int f = lane * 4;

    float dn = dis[node];
    ushort4 sv = *(const ushort4*)(in + (size_t)node * DIM + f);
    float a0 = dn * bf2f(sv.x);
    float a1 = dn * bf2f(sv.y);
    float a2 = dn * bf2f(sv.z);
    float a3 = dn * bf2f(sv.w);

    int e = rowptr[node];
    int eEnd = rowptr[node + 1];
    for (; e + 3 < eEnd; e += 4) {
        unsigned long long p0 = csr_pk[e],     p1 = csr_pk[e + 1];
        unsigned long long p2 = csr_pk[e + 2], p3 = csr_pk[e + 3];
        int s0 = (int)(unsigned)p0, s1 = (int)(unsigned)p1;
        int s2 = (int)(unsigned)p2, s3 = (int)(unsigned)p3;
        float w0 = __uint_as_float((unsigned)(p0 >> 32));
        float w1 = __uint_as_float((unsigned)(p1 >> 32));
        float w2 = __uint_as_float((unsigned)(p2 >> 32));
        float w3 = __uint_as_float((unsigned)(p3 >> 32));
        ushort4 v0 = *(const ushort4*)(in + (size_t)s0 * DIM + f);
        ushort4 v1 = *(const ushort4*)(in + (size_t)s1 * DIM + f);
        ushort4 v2 = *(const ushort4*)(in + (size_t)s2 * DIM + f);
        ushort4 v3 = *(const ushort4*)(in + (size_t)s3 * DIM + f);
        a0 += w0 * bf2f(v0.x) + w1 * bf2f(v1.x) + w2 * bf2f(v2.x) + w3 * bf2f(v3.x);
        a1 += w0 * bf2f(v0.y) + w1 * bf2f(v1.y) + w2 * bf2f(v2.y) + w3 * bf2f(v3.y);
        a2 += w0 * bf2f(v0.z) + w1 * bf2f(v1.z) + w2 * bf2f(v2.z) + w3 * bf2f(v3.z);
        a3 += w0 * bf2f(v0.w) + w1 * bf2f(v1.w) + w2 * bf2f(v2.w) + w3 * bf2f(v3.w);
    }
    for (; e < eEnd; ++e) {
        unsigned long long p0 = csr_pk[e];
        int s0 = (int)(unsigned)p0;
        float w0 = __uint_as_float((unsigned)(p0 >> 32));
        ushort4 v0 = *(const ushort4*)(in + (size_t)s0 * DIM + f);
        a0 += w0 * bf2f(v0.x);
        a1 += w0 * bf2f(v0.y);
        a2 += w0 * bf2f(v0.z);
        a3 += w0 * bf2f(v0.w);
    }
    a0 *= dn; a1 *= dn; a2 *= dn; a3 *= dn;
    *(ushort4*)(out + (size_t)node * DIM + f) =
        make_ushort4(f2bf(a0), f2bf(a1), f2bf(a2), f2bf(a3));
}

// ---------------- wide MFMA GEMM: C = relu(A @ W + b), 128x256 tile ----------------
__global__ __launch_bounds__(256) void k_gemm_wide(const unsigned short* __restrict__ A,
                                                   const unsigned short* __restrict__ Wt,
                                                   const float* __restrict__ bias,
                                                   unsigned short* __restrict__ C, int M) {
    __shared__ unsigned short As[4][128][8];   // 8 KB
    __shared__ unsigned short Bs[4][256][8];   // 16 KB

    int tid = threadIdx.x;
    int lane = tid & 63;
    int wave = tid >> 6;          // 32-row slice
    int lr = lane & 15;
    int lc = lane >> 4;

    int rowBase = blockIdx.x * 128;

    f32x4 acc[2][16] = {};

    int r = tid >> 2;             // 0..63
    int c = tid & 3;              // k-chunk

    for (int k0 = 0; k0 < DIM; k0 += 32) {
        float4 z = make_float4(0.f, 0.f, 0.f, 0.f);
        int gr0 = rowBase + r;
        int gr1 = rowBase + r + 64;
        float4 va0 = (gr0 < M) ? *(const float4*)(A + (size_t)gr0 * DIM + k0 + c * 8) : z;
        float4 va1 = (gr1 < M) ? *(const float4*)(A + (size_t)gr1 * DIM + k0 + c * 8) : z;
        *(float4*)&As[c][r][0]      = va0;
        *(float4*)&As[c][r + 64][0] = va1;
#pragma unroll
        for (int jj = 0; jj < 4; ++jj) {
            int brow = r + 64 * jj;
            *(float4*)&Bs[c][brow][0] = *(const float4*)(Wt + (size_t)brow * DIM + k0 + c * 8);
        }
        __syncthreads();

        bf16x8 af[2];
#pragma unroll
        for (int m = 0; m < 2; ++m)
            af[m] = *(const bf16x8*)&As[lc][wave * 32 + m * 16 + lr][0];
#pragma unroll
        for (int n = 0; n < 16; ++n) {
            bf16x8 bfr = *(const bf16x8*)&Bs[lc][n * 16 + lr][0];
            acc[0][n] = __builtin_amdgcn_mfma_f32_16x16x32_bf16(af[0], bfr, acc[0][n], 0, 0, 0);
            acc[1][n] = __builtin_amdgcn_mfma_f32_16x16x32_bf16(af[1], bfr, acc[1][n], 0, 0, 0);
        }
        __syncthreads();
    }

    float bv[16];
#pragma unroll
    for (int n = 0; n < 16; ++n) bv[n] = bias[n * 16 + lr];

#pragma unroll
    for (int m = 0; m < 2; ++m) {
#pragma unroll
        for (int reg = 0; reg < 4; ++reg) {
            int row = rowBase + wave * 32 + m * 16 + lc * 4 + reg;
            if (row < M) {
#pragma unroll
                for (int n = 0; n < 16; ++n) {
                    float v = fmaxf(acc[m][n][reg] + bv[n], 0.f);
                    C[(size_t)row * DIM + n * 16 + lr] = f2bf(v);
                }
            }
        }
    }
}

// ---------------- fused GEMM2 + FC + log_softmax ----------------
__global__ __launch_bounds__(256) void k_gemm_fc(const unsigned short* __restrict__ A,
                                                 const unsigned short* __restrict__ Wt,
                                                 const float* __restrict__ bias,
                                                 const float* __restrict__ Wfc,
                                                 const float* __restrict__ bfc,
                                                 float* __restrict__ out, int M) {
    __shared__ unsigned short As[4][128][8];   // 8 KB
    __shared__ unsigned short Bs[4][256][8];   // 16 KB

    int tid = threadIdx.x;
    int lane = tid & 63;
    int wave = tid >> 6;
    int lr = lane & 15;
    int lc = lane >> 4;

    int rowBase = blockIdx.x * 128;

    f32x4 acc[2][16] = {};

    int r = tid >> 2;
    int c = tid & 3;

    for (int k0 = 0; k0 < DIM; k0 += 32) {
        float4 z = make_float4(0.f, 0.f, 0.f, 0.f);
        int gr0 = rowBase + r;
        int gr1 = rowBase + r + 64;
        float4 va0 = (gr0 < M) ? *(const float4*)(A + (size_t)gr0 * DIM + k0 + c * 8) : z;
        float4 va1 = (gr1 < M) ? *(const float4*)(A + (size_t)gr1 * DIM + k0 + c * 8) : z;
        *(float4*)&As[c][r][0]      = va0;
        *(float4*)&As[c][r + 64][0] = va1;
#pragma unroll
        for (int jj = 0; jj < 4; ++jj) {
            int brow = r + 64 * jj;
            *(float4*)&Bs[c][brow][0] = *(const float4*)(Wt + (size_t)brow * DIM + k0 + c * 8);
        }
        __syncthreads();

        bf16x8 af[2];
#pragma unroll
        for (int m = 0; m < 2; ++m)
            af[m] = *(const bf16x8*)&As[lc][wave * 32 + m * 16 + lr][0];
#pragma unroll
        for (int n = 0; n < 16; ++n) {
            bf16x8 bfr = *(const bf16x8*)&Bs[lc][n * 16 + lr][0];
            acc[0][n] = __builtin_amdgcn_mfma_f32_16x16x32_bf16(af[0], bfr, acc[0][n], 0, 0, 0);
            acc[1][n] = __builtin_amdgcn_mfma_f32_16x16x32_bf16(af[1], bfr, acc[1][n], 0, 0, 0);
        }
        __syncthreads();
    }

    float bv[16], wf0[16], wf1[16];
#pragma unroll
    for (int n = 0; n < 16; ++n) {
        int col = n * 16 + lr;
        bv[n]  = bias[col];
        wf0[n] = Wfc[col * 2 + 0];
        wf1[n] = Wfc[col * 2 + 1];
    }
    float bb0 = bfc[0], bb1 = bfc[1];

#pragma unroll
    for (int m = 0; m < 2; ++m) {
#pragma unroll
        for (int reg = 0; reg < 4; ++reg) {
            int row = rowBase + wave * 32 + m * 16 + lc * 4 + reg;
            float s0 = 0.f, s1 = 0.f;
#pragma unroll
            for (int n = 0; n < 16; ++n) {
                float v = fmaxf(acc[m][n][reg] + bv[n], 0.f);   // bias + relu (h2 in f32)
                s0 += v * wf0[n];
                s1 += v * wf1[n];
            }
#pragma unroll
            for (int o = 1; o < 16; o <<= 1) {
                s0 += __shfl_xor(s0, o);
                s1 += __shfl_xor(s1, o);
            }
            if (lr == 0 && row < M) {
                float l0 = s0 + bb0;
                float l1 = s1 + bb1;
                float mx = fmaxf(l0, l1);
                float lse = mx + logf(expf(l0 - mx) + expf(l1 - mx));
                out[(size_t)row * 2 + 0] = l0 - lse;
                out[(size_t)row * 2 + 1] = l1 - lse;
            }
        }
    }
}

// ---------------- launch ----------------
extern "C" void kernel_launch(void* const* d_in, const int* in_sizes, int n_in,
                              void* d_out, int out_size, void* d_ws, size_t ws_size,
                              hipStream_t stream) {
    const float* x      = (const float*)d_in[0];
    const int* ei       = (const int*)d_in[1];   // int32 from harness
    const int* esrc     = ei;
    const int* edst     = ei + N_EDGES;
    const float* W1  = (const float*)d_in[2];
    const float* b1  = (const float*)d_in[3];
    const float* W2  = (const float*)d_in[4];
    const float* b2  = (const float*)d_in[5];
    const float* Wfc = (const float*)d_in[6];
    const float* bfc = (const float*)d_in[7];
    float* out = (float*)d_out;

    const size_t NF = (size_t)N_NODES * DIM;
    unsigned short* P0 = (unsigned short*)d_ws;          // xb, later a2b
    unsigned short* P1 = P0 + NF;                        // a1b
    unsigned short* P2 = P1 + NF;                        // h1b
    unsigned short* W1t = P2 + NF;                       // 256*256 (flat [n][k])
    unsigned short* W2t = W1t + 256 * 256;
    unsigned long long* csr_pk = (unsigned long long*)(W2t + 256 * 256);   // E (8B-aligned)
    float* dis    = (float*)(csr_pk + N_EDGES);          // N
    int* ideg     = (int*)(dis + N_NODES);               // N
    int* rowptr   = ideg + N_NODES;                      // N+1
    int* cursor   = rowptr + N_NODES + 1;                // N
    int* blocksum = cursor + N_NODES;                    // 256

    // CSR build + converts
    (void)hipMemsetAsync(ideg, 0, N_NODES * sizeof(int), stream);
    k_prep<<<NXBLK + 512 + NDEGBLK, 256, 0, stream>>>(x, P0, W1, W1t, W2, W2t, edst, ideg);
    k_scan_block<<<SCAN_BLOCKS, 256, 0, stream>>>(ideg, rowptr, blocksum);
    k_scan_add<<<SCAN_BLOCKS, 256, 0, stream>>>(rowptr, blocksum, cursor, ideg, dis);
    k_csr_fill<<<(N_EDGES + 255) / 256, 256, 0, stream>>>(esrc, edst, cursor, csr_pk, dis);

    int aggBlocks = (N_NODES + 3) / 4;
    int gemmBlocks = (N_NODES + 127) / 128;

    // layer 1
    k_agg_bf16<<<aggBlocks, 256, 0, stream>>>(P0, dis, rowptr, csr_pk, P1);
    k_gemm_wide<<<gemmBlocks, 256, 0, stream>>>(P1, W1t, b1, P2, N_NODES);

    // layer 2 + FC fused
    k_agg_bf16<<<aggBlocks, 256, 0, stream>>>(P2, dis, rowptr, csr_pk, P0);
    k_gemm_fc<<<gemmBlocks, 256, 0, stream>>>(P0, W2t, b2, Wfc, bfc, out, N_NODES);
}

// Round 13
// 271.066 us; speedup vs baseline: 1.1115x; 1.1115x over previous
//
#include <hip/hip_runtime.h>
#include <math.h>

#define N_NODES 50000
#define N_EDGES 800000
#define DIM 256
#define SCAN_BLOCKS ((N_NODES + 255) / 256)   // 196
#define NXBLK 12500                           // (N_NODES*DIM/4)/256 blocks for x convert
#define NDEGBLK ((N_EDGES + 255) / 256)       // 3125

typedef short bf16x8 __attribute__((ext_vector_type(8)));
typedef float f32x4 __attribute__((ext_vector_type(4)));

__device__ __forceinline__ float bf2f(unsigned short u) {
    return __uint_as_float(((unsigned)u) << 16);
}
__device__ __forceinline__ unsigned short f2bf(float f) {
    unsigned u = __float_as_uint(f);
    return (unsigned short)((u + 0x7fffu + ((u >> 16) & 1u)) >> 16);  // RTNE
}

// ---- fused prologue: x->bf16 + W1/W2 transpose + deg_count capturing per-edge rank ----
__global__ __launch_bounds__(256) void k_prep(const float* __restrict__ x,
                                              unsigned short* __restrict__ xb,
                                              const float* __restrict__ W1,
                                              unsigned short* __restrict__ W1t,
                                              const float* __restrict__ W2,
                                              unsigned short* __restrict__ W2t,
                                              const int* __restrict__ dst,
                                              int* __restrict__ ideg,
                                              int* __restrict__ erank) {
    int bid = blockIdx.x;
    int tid = threadIdx.x;
    if (bid < NXBLK) {
        int i = bid * 256 + tid;              // one float4 per thread
        float4 v = ((const float4*)x)[i];
        ((ushort4*)xb)[i] = make_ushort4(f2bf(v.x), f2bf(v.y), f2bf(v.z), f2bf(v.w));
    } else if (bid < NXBLK + 256) {
        int n = bid - NXBLK;
        W1t[n * 256 + tid] = f2bf(W1[tid * 256 + n]);
    } else if (bid < NXBLK + 512) {
        int n = bid - NXBLK - 256;
        W2t[n * 256 + tid] = f2bf(W2[tid * 256 + n]);
    } else {
        int e = (bid - NXBLK - 512) * 256 + tid;
        if (e < N_EDGES) erank[e] = atomicAdd(&ideg[dst[e]], 1);   // rank within dst row
    }
}

// ---------------- CSR build ----------------

__global__ __launch_bounds__(256) void k_scan_block(const int* __restrict__ ideg,
                                                    int* __restrict__ rowptr,
                                                    int* __restrict__ blocksum) {
    __shared__ int s[256];
    int t = threadIdx.x;
    int i = blockIdx.x * 256 + t;
    int v = (i < N_NODES) ? ideg[i] : 0;
    s[t] = v;
    for (int off = 1; off < 256; off <<= 1) {
        __syncthreads();
        int add = (t >= off) ? s[t - off] : 0;
        __syncthreads();
        s[t] += add;
    }
    __syncthreads();
    if (i < N_NODES) rowptr[i] = s[t] - v;
    if (t == 255) blocksum[blockIdx.x] = s[255];
}

__global__ __launch_bounds__(256) void k_scan_add(int* __restrict__ rowptr,
                                                  const int* __restrict__ blocksum,
                                                  const int* __restrict__ ideg,
                                                  float* __restrict__ dis) {
    __shared__ int s[256];
    int t = threadIdx.x;
    int v = (t < SCAN_BLOCKS) ? blocksum[t] : 0;
    s[t] = v;
    for (int off = 1; off < 256; off <<= 1) {
        __syncthreads();
        int add = (t >= off) ? s[t - off] : 0;
        __syncthreads();
        s[t] += add;
    }
    __syncthreads();
    int excl = s[t] - v;
    __syncthreads();
    s[t] = excl;
    __syncthreads();
    int off = s[blockIdx.x];

    int i = blockIdx.x * 256 + t;
    if (i < N_NODES) {
        rowptr[i] += off;
        dis[i] = rsqrtf((float)(ideg[i] + 1));
    }
    if (i == 0) rowptr[N_NODES] = N_EDGES;
}

// fill CSR: atomic-free — pos = rowptr[dst] + erank; one 8-byte scatter {src, dis[src]}
__global__ void k_csr_fill(const int* __restrict__ src, const int* __restrict__ dst,
                           const int* __restrict__ erank,
                           const int* __restrict__ rowptr,
                           unsigned long long* __restrict__ csr_pk,
                           const float* __restrict__ dis) {
    int e = blockIdx.x * blockDim.x + threadIdx.x;
    if (e < N_EDGES) {
        int s = src[e];
        int pos = rowptr[dst[e]] + erank[e];
        unsigned long long pk = (unsigned)s |
            ((unsigned long long)__float_as_uint(dis[s]) << 32);
        __builtin_nontemporal_store(pk, &csr_pk[pos]);
    }
}

// ---------------- aggregation (bf16 gather, f32 accum, packed csr stream) ----------------
__global__ __launch_bounds__(256) void k_agg_bf16(const unsigned short* __restrict__ in,
                                                  const float* __restrict__ dis,
                                                  const int* __restrict__ rowptr,
                                                  const unsigned long long* __restrict__ csr_pk,
                                                  unsigned short* __restrict__ out) {
    int node = blockIdx.x * 4 + (threadIdx.x >> 6);
    if (node >= N_NODES) return;
    int lane = threadIdx.x & 63;
    int f = lane * 4;

    float dn = dis[node];
    ushort4 sv = *(const ushort4*)(in + (size_t)node * DIM + f);
    float a0 = dn * bf2f(sv.x);
    float a1 = dn * bf2f(sv.y);
    float a2 = dn * bf2f(sv.z);
    float a3 = dn * bf2f(sv.w);

    int e = rowptr[node];
    int eEnd = rowptr[node + 1];
    for (; e + 3 < eEnd; e += 4) {
        unsigned long long p0 = csr_pk[e],     p1 = csr_pk[e + 1];
        unsigned long long p2 = csr_pk[e + 2], p3 = csr_pk[e + 3];
        int s0 = (int)(unsigned)p0, s1 = (int)(unsigned)p1;
        int s2 = (int)(unsigned)p2, s3 = (int)(unsigned)p3;
        float w0 = __uint_as_float((unsigned)(p0 >> 32));
        float w1 = __uint_as_float((unsigned)(p1 >> 32));
        float w2 = __uint_as_float((unsigned)(p2 >> 32));
        float w3 = __uint_as_float((unsigned)(p3 >> 32));
        ushort4 v0 = *(const ushort4*)(in + (size_t)s0 * DIM + f);
        ushort4 v1 = *(const ushort4*)(in + (size_t)s1 * DIM + f);
        ushort4 v2 = *(const ushort4*)(in + (size_t)s2 * DIM + f);
        ushort4 v3 = *(const ushort4*)(in + (size_t)s3 * DIM + f);
        a0 += w0 * bf2f(v0.x) + w1 * bf2f(v1.x) + w2 * bf2f(v2.x) + w3 * bf2f(v3.x);
        a1 += w0 * bf2f(v0.y) + w1 * bf2f(v1.y) + w2 * bf2f(v2.y) + w3 * bf2f(v3.y);
        a2 += w0 * bf2f(v0.z) + w1 * bf2f(v1.z) + w2 * bf2f(v2.z) + w3 * bf2f(v3.z);
        a3 += w0 * bf2f(v0.w) + w1 * bf2f(v1.w) + w2 * bf2f(v2.w) + w3 * bf2f(v3.w);
    }
    for (; e < eEnd; ++e) {
        unsigned long long p0 = csr_pk[e];
        int s0 = (int)(unsigned)p0;
        float w0 = __uint_as_float((unsigned)(p0 >> 32));
        ushort4 v0 = *(const ushort4*)(in + (size_t)s0 * DIM + f);
        a0 += w0 * bf2f(v0.x);
        a1 += w0 * bf2f(v0.y);
        a2 += w0 * bf2f(v0.z);
        a3 += w0 * bf2f(v0.w);
    }
    a0 *= dn; a1 *= dn; a2 *= dn; a3 *= dn;
    *(ushort4*)(out + (size_t)node * DIM + f) =
        make_ushort4(f2bf(a0), f2bf(a1), f2bf(a2), f2bf(a3));
}

// ---------------- wide MFMA GEMM: C = relu(A @ W + b), 128x256 tile ----------------
__global__ __launch_bounds__(256) void k_gemm_wide(const unsigned short* __restrict__ A,
                                                   const unsigned short* __restrict__ Wt,
                                                   const float* __restrict__ bias,
                                                   unsigned short* __restrict__ C, int M) {
    __shared__ unsigned short As[4][128][8];   // 8 KB
    __shared__ unsigned short Bs[4][256][8];   // 16 KB

    int tid = threadIdx.x;
    int lane = tid & 63;
    int wave = tid >> 6;          // 32-row slice
    int lr = lane & 15;
    int lc = lane >> 4;

    int rowBase = blockIdx.x * 128;

    f32x4 acc[2][16] = {};

    int r = tid >> 2;             // 0..63
    int c = tid & 3;              // k-chunk

    for (int k0 = 0; k0 < DIM; k0 += 32) {
        float4 z = make_float4(0.f, 0.f, 0.f, 0.f);
        int gr0 = rowBase + r;
        int gr1 = rowBase + r + 64;
        float4 va0 = (gr0 < M) ? *(const float4*)(A + (size_t)gr0 * DIM + k0 + c * 8) : z;
        float4 va1 = (gr1 < M) ? *(const float4*)(A + (size_t)gr1 * DIM + k0 + c * 8) : z;
        *(float4*)&As[c][r][0]      = va0;
        *(float4*)&As[c][r + 64][0] = va1;
#pragma unroll
        for (int jj = 0; jj < 4; ++jj) {
            int brow = r + 64 * jj;
            *(float4*)&Bs[c][brow][0] = *(const float4*)(Wt + (size_t)brow * DIM + k0 + c * 8);
        }
        __syncthreads();

        bf16x8 af[2];
#pragma unroll
        for (int m = 0; m < 2; ++m)
            af[m] = *(const bf16x8*)&As[lc][wave * 32 + m * 16 + lr][0];
#pragma unroll
        for (int n = 0; n < 16; ++n) {
            bf16x8 bfr = *(const bf16x8*)&Bs[lc][n * 16 + lr][0];
            acc[0][n] = __builtin_amdgcn_mfma_f32_16x16x32_bf16(af[0], bfr, acc[0][n], 0, 0, 0);
            acc[1][n] = __builtin_amdgcn_mfma_f32_16x16x32_bf16(af[1], bfr, acc[1][n], 0, 0, 0);
        }
        __syncthreads();
    }

    float bv[16];
#pragma unroll
    for (int n = 0; n < 16; ++n) bv[n] = bias[n * 16 + lr];

#pragma unroll
    for (int m = 0; m < 2; ++m) {
#pragma unroll
        for (int reg = 0; reg < 4; ++reg) {
            int row = rowBase + wave * 32 + m * 16 + lc * 4 + reg;
            if (row < M) {
#pragma unroll
                for (int n = 0; n < 16; ++n) {
                    float v = fmaxf(acc[m][n][reg] + bv[n], 0.f);
                    C[(size_t)row * DIM + n * 16 + lr] = f2bf(v);
                }
            }
        }
    }
}

// ---------------- fused GEMM2 + FC + log_softmax ----------------
__global__ __launch_bounds__(256) void k_gemm_fc(const unsigned short* __restrict__ A,
                                                 const unsigned short* __restrict__ Wt,
                                                 const float* __restrict__ bias,
                                                 const float* __restrict__ Wfc,
                                                 const float* __restrict__ bfc,
                                                 float* __restrict__ out, int M) {
    __shared__ unsigned short As[4][128][8];   // 8 KB
    __shared__ unsigned short Bs[4][256][8];   // 16 KB

    int tid = threadIdx.x;
    int lane = tid & 63;
    int wave = tid >> 6;
    int lr = lane & 15;
    int lc = lane >> 4;

    int rowBase = blockIdx.x * 128;

    f32x4 acc[2][16] = {};

    int r = tid >> 2;
    int c = tid & 3;

    for (int k0 = 0; k0 < DIM; k0 += 32) {
        float4 z = make_float4(0.f, 0.f, 0.f, 0.f);
        int gr0 = rowBase + r;
        int gr1 = rowBase + r + 64;
        float4 va0 = (gr0 < M) ? *(const float4*)(A + (size_t)gr0 * DIM + k0 + c * 8) : z;
        float4 va1 = (gr1 < M) ? *(const float4*)(A + (size_t)gr1 * DIM + k0 + c * 8) : z;
        *(float4*)&As[c][r][0]      = va0;
        *(float4*)&As[c][r + 64][0] = va1;
#pragma unroll
        for (int jj = 0; jj < 4; ++jj) {
            int brow = r + 64 * jj;
            *(float4*)&Bs[c][brow][0] = *(const float4*)(Wt + (size_t)brow * DIM + k0 + c * 8);
        }
        __syncthreads();

        bf16x8 af[2];
#pragma unroll
        for (int m = 0; m < 2; ++m)
            af[m] = *(const bf16x8*)&As[lc][wave * 32 + m * 16 + lr][0];
#pragma unroll
        for (int n = 0; n < 16; ++n) {
            bf16x8 bfr = *(const bf16x8*)&Bs[lc][n * 16 + lr][0];
            acc[0][n] = __builtin_amdgcn_mfma_f32_16x16x32_bf16(af[0], bfr, acc[0][n], 0, 0, 0);
            acc[1][n] = __builtin_amdgcn_mfma_f32_16x16x32_bf16(af[1], bfr, acc[1][n], 0, 0, 0);
        }
        __syncthreads();
    }

    float bv[16], wf0[16], wf1[16];
#pragma unroll
    for (int n = 0; n < 16; ++n) {
        int col = n * 16 + lr;
        bv[n]  = bias[col];
        wf0[n] = Wfc[col * 2 + 0];
        wf1[n] = Wfc[col * 2 + 1];
    }
    float bb0 = bfc[0], bb1 = bfc[1];

#pragma unroll
    for (int m = 0; m < 2; ++m) {
#pragma unroll
        for (int reg = 0; reg < 4; ++reg) {
            int row = rowBase + wave * 32 + m * 16 + lc * 4 + reg;
            float s0 = 0.f, s1 = 0.f;
#pragma unroll
            for (int n = 0; n < 16; ++n) {
                float v = fmaxf(acc[m][n][reg] + bv[n], 0.f);   // bias + relu (h2 in f32)
                s0 += v * wf0[n];
                s1 += v * wf1[n];
            }
#pragma unroll
            for (int o = 1; o < 16; o <<= 1) {
                s0 += __shfl_xor(s0, o);
                s1 += __shfl_xor(s1, o);
            }
            if (lr == 0 && row < M) {
                float l0 = s0 + bb0;
                float l1 = s1 + bb1;
                float mx = fmaxf(l0, l1);
                float lse = mx + logf(expf(l0 - mx) + expf(l1 - mx));
                out[(size_t)row * 2 + 0] = l0 - lse;
                out[(size_t)row * 2 + 1] = l1 - lse;
            }
        }
    }
}

// ---------------- launch ----------------
extern "C" void kernel_launch(void* const* d_in, const int* in_sizes, int n_in,
                              void* d_out, int out_size, void* d_ws, size_t ws_size,
                              hipStream_t stream) {
    const float* x      = (const float*)d_in[0];
    const int* ei       = (const int*)d_in[1];   // int32 from harness
    const int* esrc     = ei;
    const int* edst     = ei + N_EDGES;
    const float* W1  = (const float*)d_in[2];
    const float* b1  = (const float*)d_in[3];
    const float* W2  = (const float*)d_in[4];
    const float* b2  = (const float*)d_in[5];
    const float* Wfc = (const float*)d_in[6];
    const float* bfc = (const float*)d_in[7];
    float* out = (float*)d_out;

    const size_t NF = (size_t)N_NODES * DIM;
    unsigned short* P0 = (unsigned short*)d_ws;          // xb, later a2b
    unsigned short* P1 = P0 + NF;                        // a1b
    unsigned short* P2 = P1 + NF;                        // h1b
    unsigned short* W1t = P2 + NF;                       // 256*256 (flat [n][k])
    unsigned short* W2t = W1t + 256 * 256;
    unsigned long long* csr_pk = (unsigned long long*)(W2t + 256 * 256);   // E (8B-aligned)
    float* dis    = (float*)(csr_pk + N_EDGES);          // N
    int* ideg     = (int*)(dis + N_NODES);               // N
    int* rowptr   = ideg + N_NODES;                      // N+1
    int* erank    = rowptr + N_NODES + 1;                // E
    int* blocksum = erank + N_EDGES;                     // 256

    // CSR build + converts
    (void)hipMemsetAsync(ideg, 0, N_NODES * sizeof(int), stream);
    k_prep<<<NXBLK + 512 + NDEGBLK, 256, 0, stream>>>(x, P0, W1, W1t, W2, W2t, edst, ideg, erank);
    k_scan_block<<<SCAN_BLOCKS, 256, 0, stream>>>(ideg, rowptr, blocksum);
    k_scan_add<<<SCAN_BLOCKS, 256, 0, stream>>>(rowptr, blocksum, ideg, dis);
    k_csr_fill<<<(N_EDGES + 255) / 256, 256, 0, stream>>>(esrc, edst, erank, rowptr, csr_pk, dis);

    int aggBlocks = (N_NODES + 3) / 4;
    int gemmBlocks = (N_NODES + 127) / 128;

    // layer 1
    k_agg_bf16<<<aggBlocks, 256, 0, stream>>>(P0, dis, rowptr, csr_pk, P1);
    k_gemm_wide<<<gemmBlocks, 256, 0, stream>>>(P1, W1t, b1, P2, N_NODES);

    // layer 2 + FC fused
    k_agg_bf16<<<aggBlocks, 256, 0, stream>>>(P2, dis, rowptr, csr_pk, P0);
    k_gemm_fc<<<gemmBlocks, 256, 0, stream>>>(P0, W2t, b2, Wfc, bfc, out, N_NODES);
}

// Round 14
// 250.467 us; speedup vs baseline: 1.2029x; 1.0822x over previous
//
#include <hip/hip_runtime.h>
#include <math.h>

#define N_NODES 50000
#define N_EDGES 800000
#define DIM 256
#define SCAN_BLOCKS ((N_NODES + 255) / 256)   // 196
#define NXBLK 12500                           // (N_NODES*DIM/4)/256 blocks for x convert
#define NDEGBLK ((N_EDGES + 255) / 256)       // 3125

typedef short bf16x8 __attribute__((ext_vector_type(8)));
typedef float f32x4 __attribute__((ext_vector_type(4)));

__device__ __forceinline__ float bf2f(unsigned short u) {
    return __uint_as_float(((unsigned)u) << 16);
}
__device__ __forceinline__ unsigned short f2bf(float f) {
    unsigned u = __float_as_uint(f);
    return (unsigned short)((u + 0x7fffu + ((u >> 16) & 1u)) >> 16);  // RTNE
}

// ---- fused prologue: x->bf16 + W1/W2 transpose + deg_count capturing per-edge rank ----
__global__ __launch_bounds__(256) void k_prep(const float* __restrict__ x,
                                              unsigned short* __restrict__ xb,
                                              const float* __restrict__ W1,
                                              unsigned short* __restrict__ W1t,
                                              const float* __restrict__ W2,
                                              unsigned short* __restrict__ W2t,
                                              const int* __restrict__ dst,
                                              int* __restrict__ ideg,
                                              int* __restrict__ erank) {
    int bid = blockIdx.x;
    int tid = threadIdx.x;
    if (bid < NXBLK) {
        int i = bid * 256 + tid;              // one float4 per thread
        float4 v = ((const float4*)x)[i];
        ((ushort4*)xb)[i] = make_ushort4(f2bf(v.x), f2bf(v.y), f2bf(v.z), f2bf(v.w));
    } else if (bid < NXBLK + 256) {
        int n = bid - NXBLK;
        W1t[n * 256 + tid] = f2bf(W1[tid * 256 + n]);
    } else if (bid < NXBLK + 512) {
        int n = bid - NXBLK - 256;
        W2t[n * 256 + tid] = f2bf(W2[tid * 256 + n]);
    } else {
        int e = (bid - NXBLK - 512) * 256 + tid;
        if (e < N_EDGES) erank[e] = atomicAdd(&ideg[dst[e]], 1);   // rank within dst row
    }
}

// ---------------- CSR build ----------------

__global__ __launch_bounds__(256) void k_scan_block(const int* __restrict__ ideg,
                                                    int* __restrict__ rowptr,
                                                    int* __restrict__ blocksum) {
    __shared__ int s[256];
    int t = threadIdx.x;
    int i = blockIdx.x * 256 + t;
    int v = (i < N_NODES) ? ideg[i] : 0;
    s[t] = v;
    for (int off = 1; off < 256; off <<= 1) {
        __syncthreads();
        int add = (t >= off) ? s[t - off] : 0;
        __syncthreads();
        s[t] += add;
    }
    __syncthreads();
    if (i < N_NODES) rowptr[i] = s[t] - v;
    if (t == 255) blocksum[blockIdx.x] = s[255];
}

__global__ __launch_bounds__(256) void k_scan_add(int* __restrict__ rowptr,
                                                  const int* __restrict__ blocksum,
                                                  const int* __restrict__ ideg,
                                                  float* __restrict__ dis) {
    __shared__ int s[256];
    int t = threadIdx.x;
    int v = (t < SCAN_BLOCKS) ? blocksum[t] : 0;
    s[t] = v;
    for (int off = 1; off < 256; off <<= 1) {
        __syncthreads();
        int add = (t >= off) ? s[t - off] : 0;
        __syncthreads();
        s[t] += add;
    }
    __syncthreads();
    int excl = s[t] - v;
    __syncthreads();
    s[t] = excl;
    __syncthreads();
    int off = s[blockIdx.x];

    int i = blockIdx.x * 256 + t;
    if (i < N_NODES) {
        rowptr[i] += off;
        dis[i] = rsqrtf((float)(ideg[i] + 1));
    }
    if (i == 0) rowptr[N_NODES] = N_EDGES;
}

// fill CSR: atomic-free; plain store so L2 write-back can merge row-contiguous 8B writes
__global__ void k_csr_fill(const int* __restrict__ src, const int* __restrict__ dst,
                           const int* __restrict__ erank,
                           const int* __restrict__ rowptr,
                           unsigned long long* __restrict__ csr_pk,
                           const float* __restrict__ dis) {
    int e = blockIdx.x * blockDim.x + threadIdx.x;
    if (e < N_EDGES) {
        int s = src[e];
        int pos = rowptr[dst[e]] + erank[e];
        csr_pk[pos] = (unsigned)s |
            ((unsigned long long)__float_as_uint(dis[s]) << 32);
    }
}

// ---------------- aggregation (bf16 gather, f32 accum, packed csr stream) ----------------
__global__ __launch_bounds__(256) void k_agg_bf16(const unsigned short* __restrict__ in,
                                                  const float* __restrict__ dis,
                                                  const int* __restrict__ rowptr,
                                                  const unsigned long long* __restrict__ csr_pk,
                                                  unsigned short* __restrict__ out) {
    int node = blockIdx.x * 4 + (threadIdx.x >> 6);
    if (node >= N_NODES) return;
    int lane = threadIdx.x & 63;
    int f = lane * 4;

    float dn = dis[node];
    ushort4 sv = *(const ushort4*)(in + (size_t)node * DIM + f);
    float a0 = dn * bf2f(sv.x);
    float a1 = dn * bf2f(sv.y);
    float a2 = dn * bf2f(sv.z);
    float a3 = dn * bf2f(sv.w);

    int e = rowptr[node];
    int eEnd = rowptr[node + 1];
    for (; e + 3 < eEnd; e += 4) {
        unsigned long long p0 = csr_pk[e],     p1 = csr_pk[e + 1];
        unsigned long long p2 = csr_pk[e + 2], p3 = csr_pk[e + 3];
        int s0 = (int)(unsigned)p0, s1 = (int)(unsigned)p1;
        int s2 = (int)(unsigned)p2, s3 = (int)(unsigned)p3;
        float w0 = __uint_as_float((unsigned)(p0 >> 32));
        float w1 = __uint_as_float((unsigned)(p1 >> 32));
        float w2 = __uint_as_float((unsigned)(p2 >> 32));
        float w3 = __uint_as_float((unsigned)(p3 >> 32));
        ushort4 v0 = *(const ushort4*)(in + (size_t)s0 * DIM + f);
        ushort4 v1 = *(const ushort4*)(in + (size_t)s1 * DIM + f);
        ushort4 v2 = *(const ushort4*)(in + (size_t)s2 * DIM + f);
        ushort4 v3 = *(const ushort4*)(in + (size_t)s3 * DIM + f);
        a0 += w0 * bf2f(v0.x) + w1 * bf2f(v1.x) + w2 * bf2f(v2.x) + w3 * bf2f(v3.x);
        a1 += w0 * bf2f(v0.y) + w1 * bf2f(v1.y) + w2 * bf2f(v2.y) + w3 * bf2f(v3.y);
        a2 += w0 * bf2f(v0.z) + w1 * bf2f(v1.z) + w2 * bf2f(v2.z) + w3 * bf2f(v3.z);
        a3 += w0 * bf2f(v0.w) + w1 * bf2f(v1.w) + w2 * bf2f(v2.w) + w3 * bf2f(v3.w);
    }
    for (; e < eEnd; ++e) {
        unsigned long long p0 = csr_pk[e];
        int s0 = (int)(unsigned)p0;
        float w0 = __uint_as_float((unsigned)(p0 >> 32));
        ushort4 v0 = *(const ushort4*)(in + (size_t)s0 * DIM + f);
        a0 += w0 * bf2f(v0.x);
        a1 += w0 * bf2f(v0.y);
        a2 += w0 * bf2f(v0.z);
        a3 += w0 * bf2f(v0.w);
    }
    a0 *= dn; a1 *= dn; a2 *= dn; a3 *= dn;
    *(ushort4*)(out + (size_t)node * DIM + f) =
        make_ushort4(f2bf(a0), f2bf(a1), f2bf(a2), f2bf(a3));
}

// ---------------- MFMA GEMM: C = relu(A @ W + b), 64x256 tile (grid balance) ----------------
__global__ __launch_bounds__(256) void k_gemm_wide(const unsigned short* __restrict__ A,
                                                   const unsigned short* __restrict__ Wt,
                                                   const float* __restrict__ bias,
                                                   unsigned short* __restrict__ C, int M) {
    __shared__ unsigned short As[4][64][8];    // 4 KB
    __shared__ unsigned short Bs[4][256][8];   // 16 KB

    int tid = threadIdx.x;
    int lane = tid & 63;
    int wave = tid >> 6;          // 16-row slice
    int lr = lane & 15;
    int lc = lane >> 4;

    int rowBase = blockIdx.x * 64;

    f32x4 acc[16] = {};

    int r = tid >> 2;             // 0..63
    int c = tid & 3;              // k-chunk

    for (int k0 = 0; k0 < DIM; k0 += 32) {
        float4 z = make_float4(0.f, 0.f, 0.f, 0.f);
        int gr0 = rowBase + r;
        float4 va0 = (gr0 < M) ? *(const float4*)(A + (size_t)gr0 * DIM + k0 + c * 8) : z;
        *(float4*)&As[c][r][0] = va0;
#pragma unroll
        for (int jj = 0; jj < 4; ++jj) {
            int brow = r + 64 * jj;
            *(float4*)&Bs[c][brow][0] = *(const float4*)(Wt + (size_t)brow * DIM + k0 + c * 8);
        }
        __syncthreads();

        bf16x8 af = *(const bf16x8*)&As[lc][wave * 16 + lr][0];
#pragma unroll
        for (int n = 0; n < 16; ++n) {
            bf16x8 bfr = *(const bf16x8*)&Bs[lc][n * 16 + lr][0];
            acc[n] = __builtin_amdgcn_mfma_f32_16x16x32_bf16(af, bfr, acc[n], 0, 0, 0);
        }
        __syncthreads();
    }

    float bv[16];
#pragma unroll
    for (int n = 0; n < 16; ++n) bv[n] = bias[n * 16 + lr];

#pragma unroll
    for (int reg = 0; reg < 4; ++reg) {
        int row = rowBase + wave * 16 + lc * 4 + reg;
        if (row < M) {
#pragma unroll
            for (int n = 0; n < 16; ++n) {
                float v = fmaxf(acc[n][reg] + bv[n], 0.f);
                C[(size_t)row * DIM + n * 16 + lr] = f2bf(v);
            }
        }
    }
}

// ---------------- fused GEMM2 + FC + log_softmax, 64x256 tile ----------------
__global__ __launch_bounds__(256) void k_gemm_fc(const unsigned short* __restrict__ A,
                                                 const unsigned short* __restrict__ Wt,
                                                 const float* __restrict__ bias,
                                                 const float* __restrict__ Wfc,
                                                 const float* __restrict__ bfc,
                                                 float* __restrict__ out, int M) {
    __shared__ unsigned short As[4][64][8];    // 4 KB
    __shared__ unsigned short Bs[4][256][8];   // 16 KB

    int tid = threadIdx.x;
    int lane = tid & 63;
    int wave = tid >> 6;
    int lr = lane & 15;
    int lc = lane >> 4;

    int rowBase = blockIdx.x * 64;

    f32x4 acc[16] = {};

    int r = tid >> 2;
    int c = tid & 3;

    for (int k0 = 0; k0 < DIM; k0 += 32) {
        float4 z = make_float4(0.f, 0.f, 0.f, 0.f);
        int gr0 = rowBase + r;
        float4 va0 = (gr0 < M) ? *(const float4*)(A + (size_t)gr0 * DIM + k0 + c * 8) : z;
        *(float4*)&As[c][r][0] = va0;
#pragma unroll
        for (int jj = 0; jj < 4; ++jj) {
            int brow = r + 64 * jj;
            *(float4*)&Bs[c][brow][0] = *(const float4*)(Wt + (size_t)brow * DIM + k0 + c * 8);
        }
        __syncthreads();

        bf16x8 af = *(const bf16x8*)&As[lc][wave * 16 + lr][0];
#pragma unroll
        for (int n = 0; n < 16; ++n) {
            bf16x8 bfr = *(const bf16x8*)&Bs[lc][n * 16 + lr][0];
            acc[n] = __builtin_amdgcn_mfma_f32_16x16x32_bf16(af, bfr, acc[n], 0, 0, 0);
        }
        __syncthreads();
    }

    float bv[16], wf0[16], wf1[16];
#pragma unroll
    for (int n = 0; n < 16; ++n) {
        int col = n * 16 + lr;
        bv[n]  = bias[col];
        wf0[n] = Wfc[col * 2 + 0];
        wf1[n] = Wfc[col * 2 + 1];
    }
    float bb0 = bfc[0], bb1 = bfc[1];

#pragma unroll
    for (int reg = 0; reg < 4; ++reg) {
        int row = rowBase + wave * 16 + lc * 4 + reg;
        float s0 = 0.f, s1 = 0.f;
#pragma unroll
        for (int n = 0; n < 16; ++n) {
            float v = fmaxf(acc[n][reg] + bv[n], 0.f);   // bias + relu (h2 in f32)
            s0 += v * wf0[n];
            s1 += v * wf1[n];
        }
#pragma unroll
        for (int o = 1; o < 16; o <<= 1) {
            s0 += __shfl_xor(s0, o);
            s1 += __shfl_xor(s1, o);
        }
        if (lr == 0 && row < M) {
            float l0 = s0 + bb0;
            float l1 = s1 + bb1;
            float mx = fmaxf(l0, l1);
            float lse = mx + logf(expf(l0 - mx) + expf(l1 - mx));
            out[(size_t)row * 2 + 0] = l0 - lse;
            out[(size_t)row * 2 + 1] = l1 - lse;
        }
    }
}

// ---------------- launch ----------------
extern "C" void kernel_launch(void* const* d_in, const int* in_sizes, int n_in,
                              void* d_out, int out_size, void* d_ws, size_t ws_size,
                              hipStream_t stream) {
    const float* x      = (const float*)d_in[0];
    const int* ei       = (const int*)d_in[1];   // int32 from harness
    const int* esrc     = ei;
    const int* edst     = ei + N_EDGES;
    const float* W1  = (const float*)d_in[2];
    const float* b1  = (const float*)d_in[3];
    const float* W2  = (const float*)d_in[4];
    const float* b2  = (const float*)d_in[5];
    const float* Wfc = (const float*)d_in[6];
    const float* bfc = (const float*)d_in[7];
    float* out = (float*)d_out;

    const size_t NF = (size_t)N_NODES * DIM;
    unsigned short* P0 = (unsigned short*)d_ws;          // xb, later a2b
    unsigned short* P1 = P0 + NF;                        // a1b
    unsigned short* P2 = P1 + NF;                        // h1b
    unsigned short* W1t = P2 + NF;                       // 256*256 (flat [n][k])
    unsigned short* W2t = W1t + 256 * 256;
    unsigned long long* csr_pk = (unsigned long long*)(W2t + 256 * 256);   // E (8B-aligned)
    float* dis    = (float*)(csr_pk + N_EDGES);          // N
    int* ideg     = (int*)(dis + N_NODES);               // N
    int* rowptr   = ideg + N_NODES;                      // N+1
    int* erank    = rowptr + N_NODES + 1;                // E
    int* blocksum = erank + N_EDGES;                     // 256

    // CSR build + converts
    (void)hipMemsetAsync(ideg, 0, N_NODES * sizeof(int), stream);
    k_prep<<<NXBLK + 512 + NDEGBLK, 256, 0, stream>>>(x, P0, W1, W1t, W2, W2t, edst, ideg, erank);
    k_scan_block<<<SCAN_BLOCKS, 256, 0, stream>>>(ideg, rowptr, blocksum);
    k_scan_add<<<SCAN_BLOCKS, 256, 0, stream>>>(rowptr, blocksum, ideg, dis);
    k_csr_fill<<<(N_EDGES + 255) / 256, 256, 0, stream>>>(esrc, edst, erank, rowptr, csr_pk, dis);

    int aggBlocks = (N_NODES + 3) / 4;
    int gemmBlocks = (N_NODES + 63) / 64;    // 782 -> ~3.05 blocks/CU

    // layer 1
    k_agg_bf16<<<aggBlocks, 256, 0, stream>>>(P0, dis, rowptr, csr_pk, P1);
    k_gemm_wide<<<gemmBlocks, 256, 0, stream>>>(P1, W1t, b1, P2, N_NODES);

    // layer 2 + FC fused
    k_agg_bf16<<<aggBlocks, 256, 0, stream>>>(P2, dis, rowptr, csr_pk, P0);
    k_gemm_fc<<<gemmBlocks, 256, 0, stream>>>(P0, W2t, b2, Wfc, bfc, out, N_NODES);
}

// Round 15
// 236.034 us; speedup vs baseline: 1.2764x; 1.0611x over previous
//
#include <hip/hip_runtime.h>
#include <math.h>

#define N_NODES 50000
#define N_EDGES 800000
#define DIM 256
#define SCAN_BLOCKS ((N_NODES + 255) / 256)   // 196
#define NXBLK 12500                           // (N_NODES*DIM/4)/256 blocks for x convert
#define NDEGBLK ((N_EDGES + 255) / 256)       // 3125
#define GEMM_BLK ((N_NODES + 63) / 64)        // 782

typedef short bf16x8 __attribute__((ext_vector_type(8)));
typedef float f32x4 __attribute__((ext_vector_type(4)));

__device__ __forceinline__ float bf2f(unsigned short u) {
    return __uint_as_float(((unsigned)u) << 16);
}
__device__ __forceinline__ unsigned short f2bf(float f) {
    unsigned u = __float_as_uint(f);
    return (unsigned short)((u + 0x7fffu + ((u >> 16) & 1u)) >> 16);  // RTNE
}

// ---- fused prologue: x->bf16 + W1/W2 transpose + deg_count capturing per-edge rank ----
__global__ __launch_bounds__(256) void k_prep(const float* __restrict__ x,
                                              unsigned short* __restrict__ xb,
                                              const float* __restrict__ W1,
                                              unsigned short* __restrict__ W1t,
                                              const float* __restrict__ W2,
                                              unsigned short* __restrict__ W2t,
                                              const int* __restrict__ dst,
                                              int* __restrict__ ideg,
                                              int* __restrict__ erank) {
    int bid = blockIdx.x;
    int tid = threadIdx.x;
    if (bid < NXBLK) {
        int i = bid * 256 + tid;              // one float4 per thread
        float4 v = ((const float4*)x)[i];
        ((ushort4*)xb)[i] = make_ushort4(f2bf(v.x), f2bf(v.y), f2bf(v.z), f2bf(v.w));
    } else if (bid < NXBLK + 256) {
        int n = bid - NXBLK;
        W1t[n * 256 + tid] = f2bf(W1[tid * 256 + n]);
    } else if (bid < NXBLK + 512) {
        int n = bid - NXBLK - 256;
        W2t[n * 256 + tid] = f2bf(W2[tid * 256 + n]);
    } else {
        int e = (bid - NXBLK - 512) * 256 + tid;
        if (e < N_EDGES) erank[e] = atomicAdd(&ideg[dst[e]], 1);   // rank within dst row
    }
}

// ---------------- CSR build ----------------

__global__ __launch_bounds__(256) void k_scan_block(const int* __restrict__ ideg,
                                                    int* __restrict__ rowptr,
                                                    int* __restrict__ blocksum) {
    __shared__ int s[256];
    int t = threadIdx.x;
    int i = blockIdx.x * 256 + t;
    int v = (i < N_NODES) ? ideg[i] : 0;
    s[t] = v;
    for (int off = 1; off < 256; off <<= 1) {
        __syncthreads();
        int add = (t >= off) ? s[t - off] : 0;
        __syncthreads();
        s[t] += add;
    }
    __syncthreads();
    if (i < N_NODES) rowptr[i] = s[t] - v;
    if (t == 255) blocksum[blockIdx.x] = s[255];
}

__global__ __launch_bounds__(256) void k_scan_add(int* __restrict__ rowptr,
                                                  const int* __restrict__ blocksum,
                                                  const int* __restrict__ ideg,
                                                  float* __restrict__ dis) {
    __shared__ int s[256];
    int t = threadIdx.x;
    int v = (t < SCAN_BLOCKS) ? blocksum[t] : 0;
    s[t] = v;
    for (int off = 1; off < 256; off <<= 1) {
        __syncthreads();
        int add = (t >= off) ? s[t - off] : 0;
        __syncthreads();
        s[t] += add;
    }
    __syncthreads();
    int excl = s[t] - v;
    __syncthreads();
    s[t] = excl;
    __syncthreads();
    int off = s[blockIdx.x];

    int i = blockIdx.x * 256 + t;
    if (i < N_NODES) {
        rowptr[i] += off;
        dis[i] = rsqrtf((float)(ideg[i] + 1));
    }
    if (i == 0) rowptr[N_NODES] = N_EDGES;
}

// ---------------- mega: GEMM1 (y1 = xb@W1t, no epilogue) || csr_fill ----------------
__global__ __launch_bounds__(256) void k_mega(const unsigned short* __restrict__ A,
                                              const unsigned short* __restrict__ Wt,
                                              unsigned short* __restrict__ Y,
                                              const int* __restrict__ src,
                                              const int* __restrict__ dst,
                                              const int* __restrict__ erank,
                                              const int* __restrict__ rowptr,
                                              unsigned long long* __restrict__ csr_pk,
                                              const float* __restrict__ dis) {
    __shared__ unsigned short As[4][64][8];    // 4 KB
    __shared__ unsigned short Bs[4][256][8];   // 16 KB

    int bid = blockIdx.x;
    int tid = threadIdx.x;

    if (bid >= GEMM_BLK) {
        // ---- csr_fill path (atomic-free) ----
        int e = (bid - GEMM_BLK) * 256 + tid;
        if (e < N_EDGES) {
            int s = src[e];
            int pos = rowptr[dst[e]] + erank[e];
            csr_pk[pos] = (unsigned)s |
                ((unsigned long long)__float_as_uint(dis[s]) << 32);
        }
        return;
    }

    // ---- GEMM path: 64x256 tile, raw bf16 store ----
    int lane = tid & 63;
    int wave = tid >> 6;
    int lr = lane & 15;
    int lc = lane >> 4;
    int rowBase = bid * 64;

    f32x4 acc[16] = {};
    int r = tid >> 2;
    int c = tid & 3;

    for (int k0 = 0; k0 < DIM; k0 += 32) {
        float4 z = make_float4(0.f, 0.f, 0.f, 0.f);
        int gr0 = rowBase + r;
        float4 va0 = (gr0 < N_NODES) ? *(const float4*)(A + (size_t)gr0 * DIM + k0 + c * 8) : z;
        *(float4*)&As[c][r][0] = va0;
#pragma unroll
        for (int jj = 0; jj < 4; ++jj) {
            int brow = r + 64 * jj;
            *(float4*)&Bs[c][brow][0] = *(const float4*)(Wt + (size_t)brow * DIM + k0 + c * 8);
        }
        __syncthreads();

        bf16x8 af = *(const bf16x8*)&As[lc][wave * 16 + lr][0];
#pragma unroll
        for (int n = 0; n < 16; ++n) {
            bf16x8 bfr = *(const bf16x8*)&Bs[lc][n * 16 + lr][0];
            acc[n] = __builtin_amdgcn_mfma_f32_16x16x32_bf16(af, bfr, acc[n], 0, 0, 0);
        }
        __syncthreads();
    }

#pragma unroll
    for (int reg = 0; reg < 4; ++reg) {
        int row = rowBase + wave * 16 + lc * 4 + reg;
        if (row < N_NODES) {
#pragma unroll
            for (int n = 0; n < 16; ++n)
                Y[(size_t)row * DIM + n * 16 + lr] = f2bf(acc[n][reg]);
        }
    }
}

// ---------------- plain GEMM: Y = A @ W (no epilogue), 64x256 tile ----------------
__global__ __launch_bounds__(256) void k_gemm_plain(const unsigned short* __restrict__ A,
                                                    const unsigned short* __restrict__ Wt,
                                                    unsigned short* __restrict__ Y, int M) {
    __shared__ unsigned short As[4][64][8];    // 4 KB
    __shared__ unsigned short Bs[4][256][8];   // 16 KB

    int tid = threadIdx.x;
    int lane = tid & 63;
    int wave = tid >> 6;
    int lr = lane & 15;
    int lc = lane >> 4;
    int rowBase = blockIdx.x * 64;

    f32x4 acc[16] = {};
    int r = tid >> 2;
    int c = tid & 3;

    for (int k0 = 0; k0 < DIM; k0 += 32) {
        float4 z = make_float4(0.f, 0.f, 0.f, 0.f);
        int gr0 = rowBase + r;
        float4 va0 = (gr0 < M) ? *(const float4*)(A + (size_t)gr0 * DIM + k0 + c * 8) : z;
        *(float4*)&As[c][r][0] = va0;
#pragma unroll
        for (int jj = 0; jj < 4; ++jj) {
            int brow = r + 64 * jj;
            *(float4*)&Bs[c][brow][0] = *(const float4*)(Wt + (size_t)brow * DIM + k0 + c * 8);
        }
        __syncthreads();

        bf16x8 af = *(const bf16x8*)&As[lc][wave * 16 + lr][0];
#pragma unroll
        for (int n = 0; n < 16; ++n) {
            bf16x8 bfr = *(const bf16x8*)&Bs[lc][n * 16 + lr][0];
            acc[n] = __builtin_amdgcn_mfma_f32_16x16x32_bf16(af, bfr, acc[n], 0, 0, 0);
        }
        __syncthreads();
    }

#pragma unroll
    for (int reg = 0; reg < 4; ++reg) {
        int row = rowBase + wave * 16 + lc * 4 + reg;
        if (row < M) {
#pragma unroll
            for (int n = 0; n < 16; ++n)
                Y[(size_t)row * DIM + n * 16 + lr] = f2bf(acc[n][reg]);
        }
    }
}

// ---------------- agg layer1: h1 = relu(agg(y1) + b1), bf16 out ----------------
__global__ __launch_bounds__(256) void k_agg_l1(const unsigned short* __restrict__ in,
                                                const float* __restrict__ dis,
                                                const int* __restrict__ rowptr,
                                                const unsigned long long* __restrict__ csr_pk,
                                                const float* __restrict__ bias,
                                                unsigned short* __restrict__ out) {
    int node = blockIdx.x * 4 + (threadIdx.x >> 6);
    if (node >= N_NODES) return;
    int lane = threadIdx.x & 63;
    int f = lane * 4;
    float4 bv = *(const float4*)(bias + f);

    float dn = dis[node];
    ushort4 sv = *(const ushort4*)(in + (size_t)node * DIM + f);
    float a0 = dn * bf2f(sv.x);
    float a1 = dn * bf2f(sv.y);
    float a2 = dn * bf2f(sv.z);
    float a3 = dn * bf2f(sv.w);

    int e = rowptr[node];
    int eEnd = rowptr[node + 1];
    for (; e + 3 < eEnd; e += 4) {
        unsigned long long p0 = csr_pk[e],     p1 = csr_pk[e + 1];
        unsigned long long p2 = csr_pk[e + 2], p3 = csr_pk[e + 3];
        int s0 = (int)(unsigned)p0, s1 = (int)(unsigned)p1;
        int s2 = (int)(unsigned)p2, s3 = (int)(unsigned)p3;
        float w0 = __uint_as_float((unsigned)(p0 >> 32));
        float w1 = __uint_as_float((unsigned)(p1 >> 32));
        float w2 = __uint_as_float((unsigned)(p2 >> 32));
        float w3 = __uint_as_float((unsigned)(p3 >> 32));
        ushort4 v0 = *(const ushort4*)(in + (size_t)s0 * DIM + f);
        ushort4 v1 = *(const ushort4*)(in + (size_t)s1 * DIM + f);
        ushort4 v2 = *(const ushort4*)(in + (size_t)s2 * DIM + f);
        ushort4 v3 = *(const ushort4*)(in + (size_t)s3 * DIM + f);
        a0 += w0 * bf2f(v0.x) + w1 * bf2f(v1.x) + w2 * bf2f(v2.x) + w3 * bf2f(v3.x);
        a1 += w0 * bf2f(v0.y) + w1 * bf2f(v1.y) + w2 * bf2f(v2.y) + w3 * bf2f(v3.y);
        a2 += w0 * bf2f(v0.z) + w1 * bf2f(v1.z) + w2 * bf2f(v2.z) + w3 * bf2f(v3.z);
        a3 += w0 * bf2f(v0.w) + w1 * bf2f(v1.w) + w2 * bf2f(v2.w) + w3 * bf2f(v3.w);
    }
    for (; e < eEnd; ++e) {
        unsigned long long p0 = csr_pk[e];
        int s0 = (int)(unsigned)p0;
        float w0 = __uint_as_float((unsigned)(p0 >> 32));
        ushort4 v0 = *(const ushort4*)(in + (size_t)s0 * DIM + f);
        a0 += w0 * bf2f(v0.x);
        a1 += w0 * bf2f(v0.y);
        a2 += w0 * bf2f(v0.z);
        a3 += w0 * bf2f(v0.w);
    }
    a0 = fmaxf(a0 * dn + bv.x, 0.f);
    a1 = fmaxf(a1 * dn + bv.y, 0.f);
    a2 = fmaxf(a2 * dn + bv.z, 0.f);
    a3 = fmaxf(a3 * dn + bv.w, 0.f);
    *(ushort4*)(out + (size_t)node * DIM + f) =
        make_ushort4(f2bf(a0), f2bf(a1), f2bf(a2), f2bf(a3));
}

// ------- agg layer2 + FC + log_softmax: h2 = relu(agg(y2)+b2) in regs; out = lsm(h2@Wfc+bfc) -------
__global__ __launch_bounds__(256) void k_agg_l2fc(const unsigned short* __restrict__ in,
                                                  const float* __restrict__ dis,
                                                  const int* __restrict__ rowptr,
                                                  const unsigned long long* __restrict__ csr_pk,
                                                  const float* __restrict__ bias,
                                                  const float* __restrict__ Wfc,
                                                  const float* __restrict__ bfc,
                                                  float* __restrict__ out) {
    int node = blockIdx.x * 4 + (threadIdx.x >> 6);
    if (node >= N_NODES) return;
    int lane = threadIdx.x & 63;
    int f = lane * 4;
    float4 bv = *(const float4*)(bias + f);
    float4 wfa = *(const float4*)(Wfc + f * 2);        // cols f,f+1: {w00,w01,w10,w11}
    float4 wfb = *(const float4*)(Wfc + f * 2 + 4);    // cols f+2,f+3
    float bb0 = bfc[0], bb1 = bfc[1];

    float dn = dis[node];
    ushort4 sv = *(const ushort4*)(in + (size_t)node * DIM + f);
    float a0 = dn * bf2f(sv.x);
    float a1 = dn * bf2f(sv.y);
    float a2 = dn * bf2f(sv.z);
    float a3 = dn * bf2f(sv.w);

    int e = rowptr[node];
    int eEnd = rowptr[node + 1];
    for (; e + 3 < eEnd; e += 4) {
        unsigned long long p0 = csr_pk[e],     p1 = csr_pk[e + 1];
        unsigned long long p2 = csr_pk[e + 2], p3 = csr_pk[e + 3];
        int s0 = (int)(unsigned)p0, s1 = (int)(unsigned)p1;
        int s2 = (int)(unsigned)p2, s3 = (int)(unsigned)p3;
        float w0 = __uint_as_float((unsigned)(p0 >> 32));
        float w1 = __uint_as_float((unsigned)(p1 >> 32));
        float w2 = __uint_as_float((unsigned)(p2 >> 32));
        float w3 = __uint_as_float((unsigned)(p3 >> 32));
        ushort4 v0 = *(const ushort4*)(in + (size_t)s0 * DIM + f);
        ushort4 v1 = *(const ushort4*)(in + (size_t)s1 * DIM + f);
        ushort4 v2 = *(const ushort4*)(in + (size_t)s2 * DIM + f);
        ushort4 v3 = *(const ushort4*)(in + (size_t)s3 * DIM + f);
        a0 += w0 * bf2f(v0.x) + w1 * bf2f(v1.x) + w2 * bf2f(v2.x) + w3 * bf2f(v3.x);
        a1 += w0 * bf2f(v0.y) + w1 * bf2f(v1.y) + w2 * bf2f(v2.y) + w3 * bf2f(v3.y);
        a2 += w0 * bf2f(v0.z) + w1 * bf2f(v1.z) + w2 * bf2f(v2.z) + w3 * bf2f(v3.z);
        a3 += w0 * bf2f(v0.w) + w1 * bf2f(v1.w) + w2 * bf2f(v2.w) + w3 * bf2f(v3.w);
    }
    for (; e < eEnd; ++e) {
        unsigned long long p0 = csr_pk[e];
        int s0 = (int)(unsigned)p0;
        float w0 = __uint_as_float((unsigned)(p0 >> 32));
        ushort4 v0 = *(const ushort4*)(in + (size_t)s0 * DIM + f);
        a0 += w0 * bf2f(v0.x);
        a1 += w0 * bf2f(v0.y);
        a2 += w0 * bf2f(v0.z);
        a3 += w0 * bf2f(v0.w);
    }
    // h2 (f32, never materialized) + FC partial dot
    float h0 = fmaxf(a0 * dn + bv.x, 0.f);
    float h1 = fmaxf(a1 * dn + bv.y, 0.f);
    float h2 = fmaxf(a2 * dn + bv.z, 0.f);
    float h3 = fmaxf(a3 * dn + bv.w, 0.f);
    float s0 = h0 * wfa.x + h1 * wfa.z + h2 * wfb.x + h3 * wfb.z;
    float s1 = h0 * wfa.y + h1 * wfa.w + h2 * wfb.y + h3 * wfb.w;
#pragma unroll
    for (int o = 1; o < 64; o <<= 1) {
        s0 += __shfl_xor(s0, o);
        s1 += __shfl_xor(s1, o);
    }
    if (lane == 0) {
        float l0 = s0 + bb0;
        float l1 = s1 + bb1;
        float mx = fmaxf(l0, l1);
        float lse = mx + logf(expf(l0 - mx) + expf(l1 - mx));
        out[(size_t)node * 2 + 0] = l0 - lse;
        out[(size_t)node * 2 + 1] = l1 - lse;
    }
}

// ---------------- launch ----------------
extern "C" void kernel_launch(void* const* d_in, const int* in_sizes, int n_in,
                              void* d_out, int out_size, void* d_ws, size_t ws_size,
                              hipStream_t stream) {
    const float* x      = (const float*)d_in[0];
    const int* ei       = (const int*)d_in[1];   // int32 from harness
    const int* esrc     = ei;
    const int* edst     = ei + N_EDGES;
    const float* W1  = (const float*)d_in[2];
    const float* b1  = (const float*)d_in[3];
    const float* W2  = (const float*)d_in[4];
    const float* b2  = (const float*)d_in[5];
    const float* Wfc = (const float*)d_in[6];
    const float* bfc = (const float*)d_in[7];
    float* out = (float*)d_out;

    const size_t NF = (size_t)N_NODES * DIM;
    unsigned short* P0 = (unsigned short*)d_ws;          // xb, later y2
    unsigned short* P1 = P0 + NF;                        // y1
    unsigned short* P2 = P1 + NF;                        // h1
    unsigned short* W1t = P2 + NF;                       // 256*256 (flat [n][k])
    unsigned short* W2t = W1t + 256 * 256;
    unsigned long long* csr_pk = (unsigned long long*)(W2t + 256 * 256);   // E (8B-aligned)
    float* dis    = (float*)(csr_pk + N_EDGES);          // N
    int* ideg     = (int*)(dis + N_NODES);               // N
    int* rowptr   = ideg + N_NODES;                      // N+1
    int* erank    = rowptr + N_NODES + 1;                // E
    int* blocksum = erank + N_EDGES;                     // 256

    // CSR build + converts
    (void)hipMemsetAsync(ideg, 0, N_NODES * sizeof(int), stream);
    k_prep<<<NXBLK + 512 + NDEGBLK, 256, 0, stream>>>(x, P0, W1, W1t, W2, W2t, edst, ideg, erank);
    k_scan_block<<<SCAN_BLOCKS, 256, 0, stream>>>(ideg, rowptr, blocksum);
    k_scan_add<<<SCAN_BLOCKS, 256, 0, stream>>>(rowptr, blocksum, ideg, dis);

    // GEMM1 (y1 = xb@W1t) || csr_fill — one concurrent dispatch
    k_mega<<<GEMM_BLK + NDEGBLK, 256, 0, stream>>>(P0, W1t, P1,
                                                   esrc, edst, erank, rowptr, csr_pk, dis);

    int aggBlocks = (N_NODES + 3) / 4;

    // layer 1: h1 = relu(agg(y1) + b1)
    k_agg_l1<<<aggBlocks, 256, 0, stream>>>(P1, dis, rowptr, csr_pk, b1, P2);

    // layer 2: y2 = h1@W2t ; out = log_softmax(relu(agg(y2)+b2)@Wfc + bfc)
    k_gemm_plain<<<GEMM_BLK, 256, 0, stream>>>(P2, W2t, P0, N_NODES);
    k_agg_l2fc<<<aggBlocks, 256, 0, stream>>>(P0, dis, rowptr, csr_pk, b2, Wfc, bfc, out);
}